// Round 5
// baseline (525.756 us; speedup 1.0000x reference)
//
#include <hip/hip_runtime.h>
#include <hip/hip_bf16.h>

// RWKV TimeMix forward, MI355X — single mega-kernel with SOFTWARE grid barrier
// (round-4's cooperative launch failed at the driver; this needs no coop API).
// Phases: P0 prep(mix+bf16 cast) -> P1 gemm3 (k/v/r, exp epi on k)
//         -> P2 windowed scan -> P3 gemm_out.
// Co-residency proof: __launch_bounds__(256,2) => 2 blocks/CU (VGPR<=128,
// LDS 10.25KB) => capacity 512 >= grid 432, so all blocks resident and the
// spin barrier cannot deadlock. Barrier flags live in ws and are
// hipMemsetAsync-zeroed each call (capture-legal); count self-resets, gen is
// monotonic, so replays are safe.

#define T_LEN 767
#define C_DIM 768
#define SZ (768 * 768)
#define R_CHUNK 4
#define QSZ (SZ / 4)
#define NBLK 432

typedef __attribute__((ext_vector_type(4))) float f32x4;
typedef __attribute__((ext_vector_type(8))) short s16x8;
typedef __attribute__((ext_vector_type(4))) short s16x4;

__device__ __forceinline__ short bfbits(float f) {
    __hip_bfloat16 h = __float2bfloat16(f);
    return *reinterpret_cast<short*>(&h);
}

// slot = {count, gen}. Device-scope atomics (L2, cross-XCD coherent).
__device__ __forceinline__ void grid_barrier(unsigned* slot) {
    __threadfence();                       // release my writes device-wide
    __syncthreads();
    if (threadIdx.x == 0) {
        unsigned g = __hip_atomic_load(slot + 1, __ATOMIC_RELAXED,
                                       __HIP_MEMORY_SCOPE_AGENT);
        unsigned a = __hip_atomic_fetch_add(slot, 1u, __ATOMIC_ACQ_REL,
                                            __HIP_MEMORY_SCOPE_AGENT);
        if (a == NBLK - 1) {               // last arriver: reset, then release
            __hip_atomic_store(slot, 0u, __ATOMIC_RELAXED,
                               __HIP_MEMORY_SCOPE_AGENT);
            __hip_atomic_fetch_add(slot + 1, 1u, __ATOMIC_ACQ_REL,
                                   __HIP_MEMORY_SCOPE_AGENT);
        } else {
            while (__hip_atomic_load(slot + 1, __ATOMIC_ACQUIRE,
                                     __HIP_MEMORY_SCOPE_AGENT) == g)
                __builtin_amdgcn_s_sleep(1);
        }
    }
    __syncthreads();
    __threadfence();                       // acquire others' writes
}

// 64x64-tile GEMM: C[bi*64.., bj*64..] = A * B^T (row-major, K=768).
// 1-deep register prefetch; padded LDS (round-2-proven, 0 bank conflicts).
// epi: 0 plain, 1 exp(min(v,60)), 2 rows<767 only.
__device__ __forceinline__ void gemm_nt64(const __hip_bfloat16* __restrict__ A,
                                          const __hip_bfloat16* __restrict__ B,
                                          float* __restrict__ C,
                                          int bi, int bj, int epi)
{
    __shared__ __hip_bfloat16 lA[64][40];
    __shared__ __hip_bfloat16 lB[64][40];
    const int tid  = threadIdx.x;
    const int lane = tid & 63;
    const int wid  = tid >> 6;
    const int wr = wid >> 1, wc = wid & 1;  // 2x2 waves, 32x32 each
    const int srow = tid >> 2;              // staging row 0..63
    const int scol = (tid & 3) * 8;         // staging k-offset 0/8/16/24
    const int frow = lane & 15;             // MFMA A/B: row/col = lane&15
    const int kseg = (lane >> 4) * 8;       //           k = (lane>>4)*8 + j

    f32x4 acc[2][2] = {};

    const __hip_bfloat16* gA = A + (size_t)(bi * 64 + srow) * C_DIM + scol;
    const __hip_bfloat16* gB = B + (size_t)(bj * 64 + srow) * C_DIM + scol;

    s16x8 a0 = *(const s16x8*)gA;
    s16x8 b0 = *(const s16x8*)gB;
    for (int t = 0; t < 24; ++t) {
        s16x8 a1, b1;
        if (t < 23) {                       // prefetch next K-step; its latency
            a1 = *(const s16x8*)(gA + (t + 1) * 32);  // hides under MFMA below
            b1 = *(const s16x8*)(gB + (t + 1) * 32);
        }
        __syncthreads();
        *(s16x8*)&lA[srow][scol] = a0;
        *(s16x8*)&lB[srow][scol] = b0;
        __syncthreads();
        s16x8 af[2], bfr[2];
        #pragma unroll
        for (int m = 0; m < 2; ++m)
            af[m] = *(const s16x8*)&lA[wr * 32 + m * 16 + frow][kseg];
        #pragma unroll
        for (int n = 0; n < 2; ++n)
            bfr[n] = *(const s16x8*)&lB[wc * 32 + n * 16 + frow][kseg];
        #pragma unroll
        for (int m = 0; m < 2; ++m)
            #pragma unroll
            for (int n = 0; n < 2; ++n)
                acc[m][n] = __builtin_amdgcn_mfma_f32_16x16x32_bf16(
                    af[m], bfr[n], acc[m][n], 0, 0, 0);
        a0 = a1; b0 = b1;
    }

    // C/D layout: col = lane&15, row = (lane>>4)*4 + j   [m89-verified]
    int rbase = bi * 64 + wr * 32 + (lane >> 4) * 4;
    int cbase = bj * 64 + wc * 32 + (lane & 15);
    #pragma unroll
    for (int m = 0; m < 2; ++m) {
        #pragma unroll
        for (int n = 0; n < 2; ++n) {
            #pragma unroll
            for (int j = 0; j < 4; ++j) {
                int row = rbase + m * 16 + j;
                int col = cbase + n * 16;
                float v = acc[m][n][j];
                if (epi == 1) v = __expf(fminf(v, 60.f));
                if (epi != 2 || row < T_LEN)
                    C[(size_t)row * C_DIM + col] = v;
            }
        }
    }
}

__global__ __launch_bounds__(256, 2) void mega_kernel(
    const float* __restrict__ x, const float* __restrict__ td,
    const float* __restrict__ tf, const float* __restrict__ tmk,
    const float* __restrict__ tmv, const float* __restrict__ tmr,
    const float* __restrict__ Wk, const float* __restrict__ Wv,
    const float* __restrict__ Wr, const float* __restrict__ Wo,
    __hip_bfloat16* __restrict__ xkvr, __hip_bfloat16* __restrict__ Wb,
    float* __restrict__ kvr, __hip_bfloat16* __restrict__ rwkv,
    float* __restrict__ out, unsigned* __restrict__ bar)
{
    const int gt = blockIdx.x * 256 + threadIdx.x;
    const int nthr = NBLK * 256;

    // ---------------- P0: prep (mix + bf16 casts) ----------------
    for (int i = gt; i < 5 * QSZ; i += nthr) {
        int job  = i / QSZ;             // 0: mix, 1..4: Wk/Wv/Wr/Wo cast
        int base = (i - job * QSZ) * 4;
        if (job != 0) {
            const float* src = (job == 1) ? Wk : (job == 2) ? Wv
                             : (job == 3) ? Wr : Wo;
            f32x4 w = *(const f32x4*)(src + base);
            s16x4 o;
            #pragma unroll
            for (int j = 0; j < 4; ++j) o[j] = bfbits(w[j]);
            *(s16x4*)(Wb + (size_t)(job - 1) * SZ + base) = o;
            continue;
        }
        int t = base / C_DIM, c = base - t * C_DIM;
        if (t == T_LEN) {
            s16x4 z = {0, 0, 0, 0};
            *(s16x4*)(xkvr + base) = z;
            *(s16x4*)(xkvr + SZ + base) = z;
            *(s16x4*)(xkvr + 2 * SZ + base) = z;
            *(s16x4*)(rwkv + base) = z;       // pad row for P3 GEMM
            continue;
        }
        f32x4 xc = *(const f32x4*)(x + base);
        f32x4 xp = {0, 0, 0, 0};
        if (t) xp = *(const f32x4*)(x + base - C_DIM);
        f32x4 mk = *(const f32x4*)(tmk + c);
        f32x4 mv = *(const f32x4*)(tmv + c);
        f32x4 mr = *(const f32x4*)(tmr + c);
        s16x4 ok, ov, orr;
        #pragma unroll
        for (int j = 0; j < 4; ++j) {
            ok[j]  = bfbits(xc[j] * mk[j] + xp[j] * (1.f - mk[j]));
            ov[j]  = bfbits(xc[j] * mv[j] + xp[j] * (1.f - mv[j]));
            orr[j] = bfbits(xc[j] * mr[j] + xp[j] * (1.f - mr[j]));
        }
        *(s16x4*)(xkvr + base) = ok;
        *(s16x4*)(xkvr + SZ + base) = ov;
        *(s16x4*)(xkvr + 2 * SZ + base) = orr;
    }
    grid_barrier(bar);

    // ---------------- P1: k/v/r GEMMs (432 tiles, 1/block) ----------------
    {
        int z = blockIdx.x / 144, rem = blockIdx.x % 144;
        gemm_nt64(xkvr + (size_t)z * SZ, Wb + (size_t)z * SZ,
                  kvr + (size_t)z * SZ, rem / 12, rem % 12, z == 0 ? 1 : 0);
    }
    grid_barrier(bar + 2);

    // ---------------- P2: windowed decay scan ----------------
    // dm = exp(-exp(td)) <= ~0.11; dm^64 < 1e-45 -> 64-step warmup is exact.
    if (gt < 192 * 192) {
        const float* kb = kvr;
        const float* vb = kvr + SZ;
        const float* rb = kvr + 2 * SZ;
        int chunk = gt / 192;
        int d  = (gt - chunk * 192) * 4;
        int t0 = chunk * R_CHUNK;
        f32x4 dm, etf;
        {
            f32x4 tdv = *(const f32x4*)(td + d);
            f32x4 tfv = *(const f32x4*)(tf + d);
            #pragma unroll
            for (int j = 0; j < 4; ++j) {
                dm[j]  = __expf(-__expf(tdv[j]));
                etf[j] = __expf(tfv[j]);
            }
        }
        f32x4 a = {0, 0, 0, 0}, b = {0, 0, 0, 0};
        #pragma unroll 16
        for (int i = 64; i >= 1; --i) {
            int t = t0 - i;
            int tt = t < 0 ? 0 : t;
            f32x4 kk = *(const f32x4*)(kb + tt * C_DIM + d);
            f32x4 vv = *(const f32x4*)(vb + tt * C_DIM + d);
            if (t < 0) { f32x4 z = {0, 0, 0, 0}; kk = z; vv = z; }
            #pragma unroll
            for (int j = 0; j < 4; ++j) {
                a[j] = fmaf(dm[j], a[j], kk[j] * vv[j]);
                b[j] = fmaf(dm[j], b[j], kk[j]);
            }
        }
        int t1 = min(t0 + R_CHUNK, T_LEN);
        for (int t = t0; t < t1; ++t) {
            f32x4 kk = *(const f32x4*)(kb + t * C_DIM + d);
            f32x4 vv = *(const f32x4*)(vb + t * C_DIM + d);
            f32x4 rr = *(const f32x4*)(rb + t * C_DIM + d);
            s16x4 o;
            #pragma unroll
            for (int j = 0; j < 4; ++j) {
                float kv  = kk[j] * vv[j];
                float wkv = fmaf(etf[j], kv, a[j]);
                float wk  = fmaf(etf[j], kk[j], b[j]) + 1e-8f;
                float sig = 1.f / (1.f + __expf(-rr[j]));
                o[j] = bfbits(sig * wkv / wk);
                a[j] = fmaf(dm[j], a[j], kv);
                b[j] = fmaf(dm[j], b[j], kk[j]);
            }
            *(s16x4*)(rwkv + t * C_DIM + d) = o;
        }
    }
    grid_barrier(bar + 4);

    // ---------------- P3: output GEMM (144 tiles) ----------------
    if (blockIdx.x < 144)
        gemm_nt64(rwkv, Wb + (size_t)3 * SZ, out,
                  blockIdx.x / 12, blockIdx.x % 12, 2);
}

extern "C" void kernel_launch(void* const* d_in, const int* in_sizes, int n_in,
                              void* d_out, int out_size, void* d_ws, size_t ws_size,
                              hipStream_t stream)
{
    const float* x   = (const float*)d_in[0];
    const float* td  = (const float*)d_in[1];
    const float* tf  = (const float*)d_in[2];
    const float* tmk = (const float*)d_in[3];
    const float* tmv = (const float*)d_in[4];
    const float* tmr = (const float*)d_in[5];
    const float* Wk  = (const float*)d_in[6];
    const float* Wv  = (const float*)d_in[7];
    const float* Wr  = (const float*)d_in[8];
    const float* Wo  = (const float*)d_in[9];
    float* out = (float*)d_out;

    char* ws = (char*)d_ws;
    __hip_bfloat16* xkvr = (__hip_bfloat16*)ws;                        // 6*SZ B
    __hip_bfloat16* Wb   = (__hip_bfloat16*)(ws + (size_t)6 * SZ);     // 8*SZ B
    float*          kvr  = (float*)(ws + (size_t)14 * SZ);             // 12*SZ B
    __hip_bfloat16* rwkv = (__hip_bfloat16*)(ws + (size_t)26 * SZ);    // 2*SZ B
    unsigned*       bar  = (unsigned*)(ws + (size_t)28 * SZ);          // 24 B

    hipMemsetAsync(bar, 0, 24, stream);   // capture-legal; zero {count,gen}x3
    mega_kernel<<<dim3(NBLK), dim3(256), 0, stream>>>(
        x, td, tf, tmk, tmv, tmr, Wk, Wv, Wr, Wo,
        xkvr, Wb, kvr, rwkv, out, bar);
}

// Round 6
// 66.976 us; speedup vs baseline: 7.8499x; 7.8499x over previous
//
#include <hip/hip_runtime.h>
#include <hip/hip_bf16.h>

// RWKV TimeMix forward, MI355X — 4 dispatches (round-2 structure + fixes):
//   P0 prep: time-mix + bf16 cast (mix only; W stays f32 in HBM)
//   P1 gemm3: k/v/r = xm * W^T, W converted f32->bf16 IN B-staging,
//             1-deep register prefetch, exp(min(.,60)) epilogue on k
//   P2 scan: windowed decay recurrence (64-step warmup is exact in fp32)
//   P3 gemm_out: rwkv @ Wo^T, row-767 zeroed in A-staging, same prefetch
// ws: xkvr bf16 3*SZ | kvr f32 3*SZ | rwkv bf16 SZ   (11.8 MB)

#define T_LEN 767
#define C_DIM 768
#define SZ (768 * 768)
#define R_CHUNK 4

typedef __attribute__((ext_vector_type(4))) float f32x4;
typedef __attribute__((ext_vector_type(8))) short s16x8;
typedef __attribute__((ext_vector_type(4))) short s16x4;

__device__ __forceinline__ short bfbits(float f) {
    __hip_bfloat16 h = __float2bfloat16(f);
    return *reinterpret_cast<short*>(&h);
}

// P0: time-mix + cast. grid (576), 256 thr, 4 elems/thread.
__global__ __launch_bounds__(256) void prep_kernel(
    const float* __restrict__ x, const float* __restrict__ tmk,
    const float* __restrict__ tmv, const float* __restrict__ tmr,
    __hip_bfloat16* __restrict__ xkvr)
{
    int base = (blockIdx.x * 256 + threadIdx.x) * 4;
    int t = base / C_DIM, c = base - t * C_DIM;
    if (t == T_LEN) {                       // pad row: defined values for P1
        s16x4 z = {0, 0, 0, 0};
        *(s16x4*)(xkvr + base) = z;
        *(s16x4*)(xkvr + SZ + base) = z;
        *(s16x4*)(xkvr + 2 * SZ + base) = z;
        return;
    }
    f32x4 xc = *(const f32x4*)(x + base);
    f32x4 xp = {0, 0, 0, 0};
    if (t) xp = *(const f32x4*)(x + base - C_DIM);
    f32x4 mk = *(const f32x4*)(tmk + c);
    f32x4 mv = *(const f32x4*)(tmv + c);
    f32x4 mr = *(const f32x4*)(tmr + c);
    s16x4 ok, ov, orr;
    #pragma unroll
    for (int j = 0; j < 4; ++j) {
        ok[j]  = bfbits(xc[j] * mk[j] + xp[j] * (1.f - mk[j]));
        ov[j]  = bfbits(xc[j] * mv[j] + xp[j] * (1.f - mv[j]));
        orr[j] = bfbits(xc[j] * mr[j] + xp[j] * (1.f - mr[j]));
    }
    *(s16x4*)(xkvr + base) = ok;
    *(s16x4*)(xkvr + SZ + base) = ov;
    *(s16x4*)(xkvr + 2 * SZ + base) = orr;
}

// 64x64-tile GEMM: C[bi*64.., bj*64..] = A(bf16) * B(f32, cvt in staging)^T.
// Row-major, K=768, 24 K-steps of 32, 1-deep register prefetch, padded LDS.
// epi: 0 plain, 1 exp(min(v,60)), 2 = A row 767 zeroed + store rows<767 only.
__device__ __forceinline__ void gemm_nt64(const __hip_bfloat16* __restrict__ A,
                                          const float* __restrict__ B,
                                          float* __restrict__ C,
                                          int bi, int bj, int epi)
{
    __shared__ __hip_bfloat16 lA[64][40];   // +8 pad: 0 bank conflicts (r2)
    __shared__ __hip_bfloat16 lB[64][40];
    const int tid  = threadIdx.x;
    const int lane = tid & 63;
    const int wid  = tid >> 6;
    const int wr = wid >> 1, wc = wid & 1;  // 2x2 waves, 32x32 each
    const int srow = tid >> 2;              // staging row 0..63
    const int scol = (tid & 3) * 8;         // staging k-offset 0/8/16/24
    const int frow = lane & 15;             // MFMA A/B: row/col = lane&15
    const int kseg = (lane >> 4) * 8;       //           k = (lane>>4)*8 + j
    const int arow = bi * 64 + srow;
    const bool azero = (epi == 2) && (arow == T_LEN);

    f32x4 acc[2][2] = {};

    const __hip_bfloat16* gA = A + (size_t)arow * C_DIM + scol;
    const float*          gB = B + (size_t)(bj * 64 + srow) * C_DIM + scol;

    s16x8 a0 = {0,0,0,0,0,0,0,0};
    if (!azero) a0 = *(const s16x8*)gA;
    f32x4 b0l = *(const f32x4*)gB;
    f32x4 b0h = *(const f32x4*)(gB + 4);

    for (int t = 0; t < 24; ++t) {
        s16x8 a1 = {0,0,0,0,0,0,0,0};
        f32x4 b1l, b1h;
        if (t < 23) {                       // prefetch next K-step: latency
            if (!azero) a1 = *(const s16x8*)(gA + (t + 1) * 32);  // hides
            b1l = *(const f32x4*)(gB + (t + 1) * 32);             // under MFMA
            b1h = *(const f32x4*)(gB + (t + 1) * 32 + 4);
        }
        __syncthreads();
        *(s16x8*)&lA[srow][scol] = a0;
        {
            s16x8 bc;
            #pragma unroll
            for (int j = 0; j < 4; ++j) { bc[j] = bfbits(b0l[j]); bc[4 + j] = bfbits(b0h[j]); }
            *(s16x8*)&lB[srow][scol] = bc;
        }
        __syncthreads();
        s16x8 af[2], bfr[2];
        #pragma unroll
        for (int m = 0; m < 2; ++m)
            af[m] = *(const s16x8*)&lA[wr * 32 + m * 16 + frow][kseg];
        #pragma unroll
        for (int n = 0; n < 2; ++n)
            bfr[n] = *(const s16x8*)&lB[wc * 32 + n * 16 + frow][kseg];
        #pragma unroll
        for (int m = 0; m < 2; ++m)
            #pragma unroll
            for (int n = 0; n < 2; ++n)
                acc[m][n] = __builtin_amdgcn_mfma_f32_16x16x32_bf16(
                    af[m], bfr[n], acc[m][n], 0, 0, 0);
        a0 = a1; b0l = b1l; b0h = b1h;
    }

    // C/D layout: col = lane&15, row = (lane>>4)*4 + j   [m89-verified]
    int rbase = bi * 64 + wr * 32 + (lane >> 4) * 4;
    int cbase = bj * 64 + wc * 32 + (lane & 15);
    #pragma unroll
    for (int m = 0; m < 2; ++m) {
        #pragma unroll
        for (int n = 0; n < 2; ++n) {
            #pragma unroll
            for (int j = 0; j < 4; ++j) {
                int row = rbase + m * 16 + j;
                int col = cbase + n * 16;
                float v = acc[m][n][j];
                if (epi == 1) v = __expf(fminf(v, 60.f));
                if (epi != 2 || row < T_LEN)
                    C[(size_t)row * C_DIM + col] = v;
            }
        }
    }
}

__global__ __launch_bounds__(256) void gemm3_kernel(
    const __hip_bfloat16* __restrict__ xkvr, const float* __restrict__ Wk,
    const float* __restrict__ Wv, const float* __restrict__ Wr,
    float* __restrict__ kvr)
{
    int z = blockIdx.z;  // 0=k (exp epilogue), 1=v, 2=r
    const float* W = (z == 0) ? Wk : (z == 1) ? Wv : Wr;
    gemm_nt64(xkvr + (size_t)z * SZ, W, kvr + (size_t)z * SZ,
              blockIdx.x, blockIdx.y, z == 0 ? 1 : 0);
}

__global__ __launch_bounds__(256) void gemm_out_kernel(
    const __hip_bfloat16* __restrict__ rwkv, const float* __restrict__ Wo,
    float* __restrict__ out)
{
    gemm_nt64(rwkv, Wo, out, blockIdx.x, blockIdx.y, 2);
}

// P2: windowed decay scan, 4 channels/thread. dm = exp(-exp(td)) <= ~0.11;
// dm^64 < 1e-45 -> 64-step warmup from zero state is exact in fp32.
// grid (3, 192), 64 threads.
__global__ __launch_bounds__(64) void scan_kernel(
    const float* __restrict__ kb, const float* __restrict__ vb,
    const float* __restrict__ rb, const float* __restrict__ td,
    const float* __restrict__ tf, __hip_bfloat16* __restrict__ rwkv)
{
    int d  = (blockIdx.x * 64 + threadIdx.x) * 4;
    int t0 = blockIdx.y * R_CHUNK;
    f32x4 dm, etf;
    {
        f32x4 tdv = *(const f32x4*)(td + d);
        f32x4 tfv = *(const f32x4*)(tf + d);
        #pragma unroll
        for (int j = 0; j < 4; ++j) {
            dm[j]  = __expf(-__expf(tdv[j]));
            etf[j] = __expf(tfv[j]);
        }
    }
    f32x4 a = {0, 0, 0, 0}, b = {0, 0, 0, 0};
    #pragma unroll 16
    for (int i = 64; i >= 1; --i) {
        int t = t0 - i;
        int tt = t < 0 ? 0 : t;
        f32x4 kk = *(const f32x4*)(kb + tt * C_DIM + d);
        f32x4 vv = *(const f32x4*)(vb + tt * C_DIM + d);
        if (t < 0) { f32x4 z = {0, 0, 0, 0}; kk = z; vv = z; }
        #pragma unroll
        for (int j = 0; j < 4; ++j) {
            a[j] = fmaf(dm[j], a[j], kk[j] * vv[j]);
            b[j] = fmaf(dm[j], b[j], kk[j]);
        }
    }
    int t1 = min(t0 + R_CHUNK, T_LEN);
    for (int t = t0; t < t1; ++t) {
        f32x4 kk = *(const f32x4*)(kb + t * C_DIM + d);
        f32x4 vv = *(const f32x4*)(vb + t * C_DIM + d);
        f32x4 rr = *(const f32x4*)(rb + t * C_DIM + d);
        s16x4 o;
        #pragma unroll
        for (int j = 0; j < 4; ++j) {
            float kv  = kk[j] * vv[j];
            float wkv = fmaf(etf[j], kv, a[j]);
            float wk  = fmaf(etf[j], kk[j], b[j]) + 1e-8f;
            float sig = 1.f / (1.f + __expf(-rr[j]));
            o[j] = bfbits(sig * wkv / wk);
            a[j] = fmaf(dm[j], a[j], kv);
            b[j] = fmaf(dm[j], b[j], kk[j]);
        }
        *(s16x4*)(rwkv + t * C_DIM + d) = o;
    }
}

extern "C" void kernel_launch(void* const* d_in, const int* in_sizes, int n_in,
                              void* d_out, int out_size, void* d_ws, size_t ws_size,
                              hipStream_t stream)
{
    const float* x   = (const float*)d_in[0];
    const float* td  = (const float*)d_in[1];
    const float* tf  = (const float*)d_in[2];
    const float* tmk = (const float*)d_in[3];
    const float* tmv = (const float*)d_in[4];
    const float* tmr = (const float*)d_in[5];
    const float* Wk  = (const float*)d_in[6];
    const float* Wv  = (const float*)d_in[7];
    const float* Wr  = (const float*)d_in[8];
    const float* Wo  = (const float*)d_in[9];
    float* out = (float*)d_out;

    char* ws = (char*)d_ws;
    __hip_bfloat16* xkvr = (__hip_bfloat16*)ws;                      // 6*SZ B
    float*          kvr  = (float*)(ws + (size_t)6 * SZ);            // 12*SZ B
    __hip_bfloat16* rwkv = (__hip_bfloat16*)(ws + (size_t)18 * SZ);  // 2*SZ B

    prep_kernel<<<dim3(SZ / 1024), 256, 0, stream>>>(x, tmk, tmv, tmr, xkvr);
    gemm3_kernel<<<dim3(12, 12, 3), 256, 0, stream>>>(xkvr, Wk, Wv, Wr, kvr);
    scan_kernel<<<dim3(3, 192), 64, 0, stream>>>(
        kvr, kvr + SZ, kvr + 2 * SZ, td, tf, rwkv);
    gemm_out_kernel<<<dim3(12, 12), 256, 0, stream>>>(rwkv, Wo, out);
}